// Round 9
// baseline (302.745 us; speedup 1.0000x reference)
//
#include <hip/hip_runtime.h>
#include <math.h>

// Bahdanau attention, B=32, T=2048, D=512, U=512, fp32 in/out.
// Round 16: flash-style fold. score_fused blocks own COMPLETE scores for
// their 128 rows (full-U structure), so each block now also computes local
// softmax stats (m_j, S_j) and an unnormalized partial context
// c_j[d] = sum_t exp(s_t-m_j)*values[t,d] by re-reading its own 128x512
// tile (L2/L3-hot, just streamed). A tiny finalize kernel combines the 16
// partials per batch (flash second level) and emits context + weights.
// This deletes softmax_context's 128MB values re-read. Score k-loop is
// r10-verbatim (98us, verified stable r10/r15).

#define B_ 32
#define T_ 2048
#define D_ 512
#define U_ 512
#define M_ (B_ * T_)

typedef _Float16 half8 __attribute__((ext_vector_type(8)));
typedef float floatx4 __attribute__((ext_vector_type(4)));

__device__ __forceinline__ float fast_tanh(float x) {
  x = fminf(fmaxf(x, -20.f), 20.f);
  const float e = __expf(2.f * x);
  return 1.f - 2.f / (e + 1.f);
}

__device__ __forceinline__ void load_lds16f(const float* g, float* l) {
  __builtin_amdgcn_global_load_lds(
      (const __attribute__((address_space(1))) void*)g,
      (__attribute__((address_space(3))) void*)l, 16, 0, 0);
}

__device__ __forceinline__ void load_lds16h(const _Float16* g, _Float16* l) {
  __builtin_amdgcn_global_load_lds(
      (const __attribute__((address_space(1))) void*)g,
      (__attribute__((address_space(3))) void*)l, 16, 0, 0);
}

// ---------------- prep: W1->w1t | projq ------------------------------------
// blocks [0,64): W1 [k][u] -> w1t [u][k] f16 (64 x 64x64 tiles)
// blocks [64,128): projq = query@W2+b2
__global__ __launch_bounds__(256) void prep_fused(
    const float* __restrict__ W1, const float* __restrict__ query,
    const float* __restrict__ W2, const float* __restrict__ b2,
    _Float16* __restrict__ w1t, float* __restrict__ projq) {
  __shared__ float sh[64 * 65];
  const int bx = blockIdx.x;
  const int tid = threadIdx.x;
  if (bx < 64) {
    const int t = bx;
    const int k0 = (t >> 3) * 64, u0 = (t & 7) * 64;
    float(*sm)[65] = (float(*)[65])sh;
    const int lu = tid & 63;
    const int g = tid >> 6;
#pragma unroll
    for (int i = 0; i < 16; ++i) {
      const int row = g * 16 + i;
      sm[row][lu] = W1[(long)(k0 + row) * U_ + u0 + lu];
    }
    __syncthreads();
#pragma unroll
    for (int i = 0; i < 16; ++i) {
      const int row = g * 16 + i;
      w1t[(long)(u0 + row) * D_ + k0 + lu] = (_Float16)sm[lu][row];
    }
  } else {
    const int t = bx - 64;  // [0,64)
    const int b = t >> 1;
    const int u = (t & 1) * 256 + tid;
    for (int d = tid; d < D_; d += 256) sh[d] = query[b * D_ + d];
    __syncthreads();
    float acc = 0.f;
#pragma unroll 8
    for (int d = 0; d < D_; ++d) acc += sh[d] * W2[d * U_ + u];
    projq[b * U_ + u] = acc + b2[u];
  }
}

// ---------------- scores + partial context, 128m x 512u per block ----------
// (k-loop is r10-verbatim.)
// Grid M/128 = 512 blocks, 512 threads = 8 waves (2m x 4u).
// Wave = 64m x 128u via 4x8 grid of 16x16x32 MFMA (acc 128 regs).
// A: values fp32 -> LDS [128][32] f32 via global_load_lds, double-buffered,
//    source-side XOR chunk swizzle (slot s of row r holds chunk s^(r&7)).
//    Fragments read as 2x float4 + in-register cvt to half8 (RTE).
// B: w1t [u][k] f16 -> LDS [512][32] halves via global_load_lds, double-
//    buffered, source-side swizzle (slot s of row r holds chunk s^(r&3)).
// Frag layouts (verified r2-r6): A[m=lane&15][k=(lane>>4)*8+j],
// B[k=(lane>>4)*8+j][n=lane&15], C[row=(lane>>4)*4+reg][col=lane&15].
// Post-loop: local softmax stats over the block's 128 complete scores +
// unnormalized partial context via L2/L3-hot re-read of the values tile.
__global__ __launch_bounds__(512, 1) void score_fused(
    const float* __restrict__ values, const _Float16* __restrict__ w1t,
    const float* __restrict__ b1, const float* __restrict__ projq,
    const float* __restrict__ V, float* __restrict__ scores,
    float* __restrict__ cpart, float* __restrict__ pms) {
  const int m0 = blockIdx.x * 128;
  const int b = blockIdx.x >> 4;  // 2048/128 = 16 row-blocks per batch
  const int tid = threadIdx.x;
  const int lane = tid & 63;
  const int w = tid >> 6;          // 0..7
  const int wm = (w & 1) * 64;     // m-half
  const int wu = (w >> 1) * 128;   // u-quarter
  const int ln = lane & 15;
  const int lq = lane >> 4;

  __shared__ alignas(16) float As[2][128 * 32];     // 32 KB dbuf
  __shared__ alignas(16) _Float16 Bs[2][512 * 32];  // 64 KB dbuf
  __shared__ float red[4][128];                     // 2 KB
  __shared__ float sc[128], ev[128];                // 1 KB
  __shared__ float4 part[512];                      // 8 KB

  // A-DMA: wave w stages rows [16w,16w+16) per step, 2 instrs of 8 rows.
  const int dr = lane >> 3;
  const int dc = (lane & 7) ^ dr;
  const float* gA[2];
#pragma unroll
  for (int j = 0; j < 2; ++j) {
    const int r = w * 16 + j * 8 + dr;
    gA[j] = values + (long)(m0 + r) * D_ + dc * 4;
  }

  // B-DMA: wave w stages rows [64w,64w+64) per step, 4 instrs of 16 rows.
  const int br = lane >> 2;
  const int bc = (lane & 3) ^ (br & 3);
  const _Float16* gB[4];
#pragma unroll
  for (int i = 0; i < 4; ++i) {
    const int r = w * 64 + i * 16 + br;
    gB[i] = w1t + (long)r * D_ + bc * 8;
  }

  floatx4 acc[4][8] = {};

  // prologue: stage k-step 0 into buf 0
#pragma unroll
  for (int j = 0; j < 2; ++j)
    load_lds16f(gA[j], &As[0][(w * 16 + j * 8) * 32]);
#pragma unroll
  for (int i = 0; i < 4; ++i)
    load_lds16h(gB[i], &Bs[0][(w * 64 + i * 16) * 32]);
  __syncthreads();

  for (int t = 0; t < 16; ++t) {
    const int p = t & 1;
    if (t < 15) {
#pragma unroll
      for (int j = 0; j < 2; ++j)
        load_lds16f(gA[j] + (t + 1) * 32, &As[p ^ 1][(w * 16 + j * 8) * 32]);
#pragma unroll
      for (int i = 0; i < 4; ++i)
        load_lds16h(gB[i] + (t + 1) * 32, &Bs[p ^ 1][(w * 64 + i * 16) * 32]);
    }
    half8 bf[8];
#pragma unroll
    for (int ni = 0; ni < 8; ++ni) {
      const int r = wu + ni * 16 + ln;
      bf[ni] = *(const half8*)&Bs[p][r * 32 + ((lq ^ (ln & 3)) * 8)];
    }
    half8 af[4];
#pragma unroll
    for (int mi = 0; mi < 4; ++mi) {
      const int r = wm + mi * 16 + ln;
      const float* row = &As[p][r * 32];
      const float4 lo = *(const float4*)(row + (((2 * lq) ^ (r & 7)) * 4));
      const float4 hi = *(const float4*)(row + (((2 * lq + 1) ^ (r & 7)) * 4));
      af[mi] = half8{(_Float16)lo.x, (_Float16)lo.y, (_Float16)lo.z,
                     (_Float16)lo.w, (_Float16)hi.x, (_Float16)hi.y,
                     (_Float16)hi.z, (_Float16)hi.w};
    }
#pragma unroll
    for (int mi = 0; mi < 4; ++mi)
#pragma unroll
      for (int ni = 0; ni < 8; ++ni)
        acc[mi][ni] = __builtin_amdgcn_mfma_f32_16x16x32_f16(
            af[mi], bf[ni], acc[mi][ni], 0, 0, 0);
    __syncthreads();
  }

  // Epilogue: full row scores (each block owns its 128 rows exclusively).
  float pre[8], vv[8];
#pragma unroll
  for (int ni = 0; ni < 8; ++ni) {
    const int u = wu + ni * 16 + ln;
    pre[ni] = b1[u] + projq[b * U_ + u];
    vv[ni] = V[u];
  }
#pragma unroll
  for (int mi = 0; mi < 4; ++mi) {
#pragma unroll
    for (int r = 0; r < 4; ++r) {
      float t = 0.f;
#pragma unroll
      for (int ni = 0; ni < 8; ++ni)
        t += fast_tanh(acc[mi][ni][r] + pre[ni]) * vv[ni];
      t += __shfl_xor(t, 1);
      t += __shfl_xor(t, 2);
      t += __shfl_xor(t, 4);
      t += __shfl_xor(t, 8);
      if (ln == 0) red[w >> 1][wm + mi * 16 + lq * 4 + r] = t;
    }
  }
  __syncthreads();
  if (tid < 128) {
    const float s = red[0][tid] + red[1][tid] + red[2][tid] + red[3][tid];
    scores[m0 + tid] = s;
    sc[tid] = s;
  }
  __syncthreads();

  // ---- local softmax stats (broadcast LDS reads; deterministic) ----
  float m = -INFINITY;
#pragma unroll 8
  for (int i = 0; i < 128; ++i) m = fmaxf(m, sc[i]);
  if (tid < 128) ev[tid] = __expf(sc[tid] - m);
  __syncthreads();
  float S = 0.f;
#pragma unroll 8
  for (int i = 0; i < 128; ++i) S += ev[i];

  // ---- partial context: c[d] = sum_t ev[t] * values[m0+t][d] ----
  // 4 row-groups (g) x 128 float4-cols (dx); rows r = 4*i+g (coalesced).
  const int g = tid >> 7;
  const int dx = tid & 127;
  float4 a4 = make_float4(0.f, 0.f, 0.f, 0.f);
  const float4* vp = (const float4*)(values + (long)(m0 + g) * D_) + dx;
#pragma unroll 8
  for (int i = 0; i < 32; ++i) {
    const float4 x = vp[(long)(4 * i) * (D_ / 4)];
    const float wgt = ev[4 * i + g];
    a4.x += wgt * x.x; a4.y += wgt * x.y; a4.z += wgt * x.z; a4.w += wgt * x.w;
  }
  part[tid] = a4;
  __syncthreads();
  if (tid < 128) {
    const float4 p0 = part[dx], p1 = part[dx + 128];
    const float4 p2 = part[dx + 256], p3 = part[dx + 384];
    float4 tot;
    tot.x = p0.x + p1.x + p2.x + p3.x;
    tot.y = p0.y + p1.y + p2.y + p3.y;
    tot.z = p0.z + p1.z + p2.z + p3.z;
    tot.w = p0.w + p1.w + p2.w + p3.w;
    *(float4*)&cpart[(long)blockIdx.x * D_ + dx * 4] = tot;
  }
  if (tid == 0) {
    pms[blockIdx.x * 2 + 0] = m;
    pms[blockIdx.x * 2 + 1] = S;
  }
}

// ---------------- finalize: combine 16 partials per batch ------------------
// Grid B_ blocks x 256 threads. Flash second level:
// M = max_j m_j, denom = sum_j e^{m_j-M} S_j,
// context = sum_j e^{m_j-M} c_j / denom, weights = e^{s-M}/denom.
__global__ __launch_bounds__(256) void finalize_kernel(
    const float* __restrict__ scores, const float* __restrict__ cpart,
    const float* __restrict__ pms, float* __restrict__ weights,
    float* __restrict__ context) {
  const int b = blockIdx.x;
  const int tid = threadIdx.x;
  __shared__ float sM[16], sS[16];
  if (tid < 16) {
    sM[tid] = pms[(b * 16 + tid) * 2 + 0];
    sS[tid] = pms[(b * 16 + tid) * 2 + 1];
  }
  __syncthreads();
  float M = -INFINITY;
#pragma unroll
  for (int j = 0; j < 16; ++j) M = fmaxf(M, sM[j]);
  float denom = 0.f;
#pragma unroll
  for (int j = 0; j < 16; ++j) denom += __expf(sM[j] - M) * sS[j];
  const float inv = 1.f / denom;

  // context: 512 d over 256 threads, float2 each.
  float c0 = 0.f, c1 = 0.f;
#pragma unroll
  for (int j = 0; j < 16; ++j) {
    const float f = __expf(sM[j] - M);
    const float2 cc = *(const float2*)&cpart[(long)(b * 16 + j) * D_ + tid * 2];
    c0 += f * cc.x;
    c1 += f * cc.y;
  }
  context[b * D_ + tid * 2 + 0] = c0 * inv;
  context[b * D_ + tid * 2 + 1] = c1 * inv;

  // weights: 2048 t over 256 threads.
#pragma unroll
  for (int i = 0; i < 8; ++i) {
    const int t = i * 256 + tid;
    weights[b * T_ + t] = __expf(scores[b * T_ + t] - M) * inv;
  }
}

extern "C" void kernel_launch(void* const* d_in, const int* in_sizes, int n_in,
                              void* d_out, int out_size, void* d_ws, size_t ws_size,
                              hipStream_t stream) {
  const float* values = (const float*)d_in[0];
  const float* query = (const float*)d_in[1];
  const float* W1 = (const float*)d_in[2];
  const float* b1 = (const float*)d_in[3];
  const float* W2 = (const float*)d_in[4];
  const float* b2 = (const float*)d_in[5];
  const float* V = (const float*)d_in[6];
  // d_in[7] = bV: unused — softmax is shift-invariant.

  float* out = (float*)d_out;
  float* context = out;            // [32,512]
  float* weights = out + B_ * D_;  // [32,2048]
  float* projq = (float*)d_ws;                                   // 64KB
  float* scores = projq + B_ * U_;                               // 256KB
  _Float16* w1t = (_Float16*)((char*)d_ws + 65536 + 262144);     // 512KB
  float* cpart = (float*)((char*)d_ws + 851968);                 // 1MB
  float* pms = (float*)((char*)d_ws + 851968 + 1048576);         // 4KB

  prep_fused<<<128, 256, 0, stream>>>(W1, query, W2, b2, w1t, projq);
  score_fused<<<M_ / 128, 512, 0, stream>>>(values, w1t, b1, projq, V, scores,
                                            cpart, pms);
  finalize_kernel<<<B_, 256, 0, stream>>>(scores, cpart, pms, weights,
                                          context);
}